// Round 8
// baseline (51.875 us; speedup 1.0000x reference)
//
#include <hip/hip_runtime.h>
#include <hip/hip_bf16.h>

// Problem constants
#define BATCH 32768
#define NIN   256
#define NOUT  256
// degrees 1..8 via MFMA; degree 0 (T_0 = 1) folded into per-column bias

typedef __attribute__((ext_vector_type(8))) short bf16x8;
typedef __attribute__((ext_vector_type(4))) float f32x4;
typedef __attribute__((ext_vector_type(2))) float f32x2;
typedef __attribute__((ext_vector_type(4))) unsigned int u32x4;

static __device__ __forceinline__ unsigned short bf16_rne(float f) {
  unsigned u = __float_as_uint(f);
  u += 0x7fffu + ((u >> 16) & 1u);
  return (unsigned short)(u >> 16);
}

// fast tanh: t = sign(v) * (1 - z) / (1 + z), z = exp(-2|v|)
static __device__ __forceinline__ float fast_tanh(float v) {
  float a = fabsf(v);
  float z = __expf(-2.0f * a);
  float r = (1.0f - z) * __builtin_amdgcn_rcpf(1.0f + z);
  return copysignf(r, v);
}

static __device__ __forceinline__ unsigned pack_pair(f32x2 v) {
  __hip_bfloat162 h2 = __float22bfloat162_rn(make_float2(v[0], v[1]));
  union { __hip_bfloat162 h; unsigned u; } cv;
  cv.h = h2;
  return cv.u;
}

static __device__ __forceinline__ void init_state(const f32x4 x0, const f32x4 x1,
                                                  f32x2* cur, f32x2* prev,
                                                  f32x2* t2) {
  #pragma unroll
  for (int p = 0; p < 4; ++p) {
    float va = (p < 2) ? x0[2 * p]     : x1[2 * p - 4];
    float vb = (p < 2) ? x0[2 * p + 1] : x1[2 * p - 3];
    float ta = fast_tanh(va);
    float tb = fast_tanh(vb);
    cur[p]  = (f32x2){ta, tb};        // T_1
    t2[p]   = cur[p] + cur[p];
    prev[p] = (f32x2){1.0f, 1.0f};    // T_0
  }
}

// Barrier that does NOT drain vmcnt (T4): cross-wave correctness here only
// needs the LDS writes visible (lgkmcnt). Global loads stay in flight.
static __device__ __forceinline__ void pipeline_barrier() {
  __builtin_amdgcn_sched_barrier(0);
  asm volatile("s_waitcnt lgkmcnt(0)" ::: "memory");
  __builtin_amdgcn_s_barrier();
  __builtin_amdgcn_sched_barrier(0);
}

// ---------------------------------------------------------------------------
// Prepack: Bp[((dm*8+ic)*16+tile)*512 + kg*128 + col*8 + j] =
//          bf16( c_basis[n][i][dm+1] * c_act[n][i] )
//   with i = ic*32 + kg*8 + j,  n = tile*16 + col.
// ---------------------------------------------------------------------------
__global__ void cheby_prepack(const float* __restrict__ cb,
                              const float* __restrict__ ca,
                              unsigned short* __restrict__ Bp) {
  int tid = blockIdx.x * 256 + threadIdx.x;
  int j    = tid & 7;
  int col  = (tid >> 3) & 15;
  int kg   = (tid >> 7) & 3;
  int tile = (tid >> 9) & 15;
  int ic   = (tid >> 13) & 7;
  int dm   = tid >> 16;           // d-1, 0..7
  int i = ic * 32 + kg * 8 + j;
  int n = tile * 16 + col;
  float w = cb[n * (NIN * 9) + i * 9 + (dm + 1)] * ca[n * NIN + i];
  Bp[tid] = bf16_rne(w);
}

// bias[n] = sum_i c_basis[n][i][0] * c_act[n][i]   (T_0 == 1 term)
__global__ void cheby_bias(const float* __restrict__ cb,
                           const float* __restrict__ ca,
                           float* __restrict__ bias) {
  int n = blockIdx.x;
  int l = threadIdx.x;            // 64 threads = one wave
  float s = 0.0f;
  #pragma unroll
  for (int k = 0; k < 4; ++k) {
    int i = l + k * 64;
    s += cb[n * (NIN * 9) + i * 9] * ca[n * NIN + i];
  }
  #pragma unroll
  for (int off = 32; off; off >>= 1) s += __shfl_down(s, off);
  if (l == 0) bias[n] = s;
}

// ---------------------------------------------------------------------------
// Fused cheby + GEMM, counted-vmcnt pipelined (T3+T4 via auto-waitcnt).
// Grid: 512 blocks x 256 threads (4 waves). Block tile: 64 rows x 256 cols
// (block spans ALL cols -> basis computed once per x element globally).
// Per ic: [issue ALL 32 B-frag loads into regs] -> [basis(ic+1) VALU +
// ds_writes cover the L2 latency] -> sched_barrier -> [pure MFMA d-loop
// with reg-double-buffered A frags] -> lgkm-only barrier.
// Compiler emits counted vmcnt/lgkmcnt waits for the hoisted loads.
// ---------------------------------------------------------------------------
__global__ __launch_bounds__(256, 2)
void cheby_mfma(const float* __restrict__ x,
                const unsigned short* __restrict__ Bp,
                const float* __restrict__ bias,
                float* __restrict__ out) {
  // [buf][d-1][mt][frag: kg*256B + row16*16B]  -- 1KB fragments, 64KB total
  __shared__ unsigned short Asm[2][8][4][512];

  int tid  = threadIdx.x;
  int w    = tid >> 6;
  int lane = tid & 63;
  int row16 = lane & 15;          // A row / B col / C-D col
  int kg    = lane >> 4;          // k-group 0..3

  int base_row = blockIdx.x * 64;
  int tile0    = w * 4;           // wave's 4 column tiles (64 cols)

  // writer role: wave w covers rows w*16..w*16+15 (plane mt=w)
  const float* xw = x + (size_t)(base_row + w * 16 + row16) * NIN + kg * 8;
  char* wbase = (char*)Asm + (w * 1024 + lane * 16);
  // reader
  const char* abase   = (const char*)Asm + lane * 16;
  const char* bp_lane = (const char*)Bp + kg * 256 + row16 * 16;

  f32x4 acc[4][4];
  #pragma unroll
  for (int a = 0; a < 4; ++a)
    #pragma unroll
    for (int b = 0; b < 4; ++b) acc[a][b] = (f32x4)0.0f;

  // ---- prologue: compute + write buf0 for ic=0 ----
  f32x4 xa = *(const f32x4*)xw;
  f32x4 xb = *(const f32x4*)(xw + 4);
  {
    f32x2 cur[4], prev[4], t2[4];
    init_state(xa, xb, cur, prev, t2);
    #pragma unroll
    for (int d = 1; d <= 8; ++d) {
      u32x4 pk;
      #pragma unroll
      for (int p = 0; p < 4; ++p) pk[p] = pack_pair(cur[p]);
      *(u32x4*)(wbase + (d - 1) * 4096) = pk;
      if (d < 8) {
        #pragma unroll
        for (int p = 0; p < 4; ++p) {
          f32x2 nx = __builtin_elementwise_fma(t2[p], cur[p], -prev[p]);
          prev[p] = cur[p];
          cur[p]  = nx;
        }
      }
    }
  }
  // x for ic=1 (consumed at top of iteration 0)
  xa = *(const f32x4*)(xw + 32);
  xb = *(const f32x4*)(xw + 36);
  pipeline_barrier();

  // ---- main loop ----
  for (int ic = 0; ic < 7; ++ic) {
    int buf = ic & 1;
    // (1) issue ALL B-fragment loads for this ic NOW (32 in flight;
    //     consumed per-d below with compiler-counted vmcnt waits)
    const char* bpi = bp_lane + (size_t)(ic * 16 + tile0) * 1024;
    bf16x8 bfr[8][4];
    #pragma unroll
    for (int dd = 0; dd < 8; ++dd)
      #pragma unroll
      for (int nt = 0; nt < 4; ++nt)
        bfr[dd][nt] = *(const bf16x8*)(bpi + (size_t)dd * 131072 + nt * 1024);

    // (2) basis for ic+1 -> buf^1 (VALU + ds_writes hide the B-load latency)
    f32x2 cur[4], prev[4], t2[4];
    init_state(xa, xb, cur, prev, t2);
    char* wp = wbase + (buf ^ 1) * 32768;
    #pragma unroll
    for (int d = 1; d <= 8; ++d) {
      u32x4 pk;
      #pragma unroll
      for (int p = 0; p < 4; ++p) pk[p] = pack_pair(cur[p]);
      *(u32x4*)(wp + (d - 1) * 4096) = pk;
      if (d < 8) {
        #pragma unroll
        for (int p = 0; p < 4; ++p) {
          f32x2 nx = __builtin_elementwise_fma(t2[p], cur[p], -prev[p]);
          prev[p] = cur[p];
          cur[p]  = nx;
        }
      }
    }
    // (3) x prefetch for ic+2 (lands under the d-loop; survives the
    //     lgkm-only barrier)
    if (ic < 6) {
      xa = *(const f32x4*)(xw + (ic + 2) * 32);
      xb = *(const f32x4*)(xw + (ic + 2) * 32 + 4);
    }
    // pin: loads + basis stay above, MFMA phase below
    __builtin_amdgcn_sched_barrier(0);

    // (4) pure MFMA d-loop; A frags double-buffered in regs
    const char* ai = abase + buf * 32768;
    bf16x8 afc[4];
    #pragma unroll
    for (int mt = 0; mt < 4; ++mt)
      afc[mt] = *(const bf16x8*)(ai + mt * 1024);
    #pragma unroll
    for (int d = 0; d < 8; ++d) {
      bf16x8 afn[4];
      if (d < 7) {
        #pragma unroll
        for (int mt = 0; mt < 4; ++mt)
          afn[mt] = *(const bf16x8*)(ai + (d + 1) * 4096 + mt * 1024);
      }
      __builtin_amdgcn_s_setprio(1);
      #pragma unroll
      for (int mt = 0; mt < 4; ++mt)
        #pragma unroll
        for (int nt = 0; nt < 4; ++nt)
          acc[mt][nt] = __builtin_amdgcn_mfma_f32_16x16x32_bf16(
              afc[mt], bfr[d][nt], acc[mt][nt], 0, 0, 0);
      __builtin_amdgcn_s_setprio(0);
      if (d < 7) {
        #pragma unroll
        for (int mt = 0; mt < 4; ++mt) afc[mt] = afn[mt];
      }
    }
    pipeline_barrier();
  }

  // ---- final iteration ic=7: MFMA only (buf=1) ----
  {
    const char* bpi = bp_lane + (size_t)(7 * 16 + tile0) * 1024;
    bf16x8 bfr[8][4];
    #pragma unroll
    for (int dd = 0; dd < 8; ++dd)
      #pragma unroll
      for (int nt = 0; nt < 4; ++nt)
        bfr[dd][nt] = *(const bf16x8*)(bpi + (size_t)dd * 131072 + nt * 1024);
    const char* ai = abase + 32768;
    bf16x8 afc[4];
    #pragma unroll
    for (int mt = 0; mt < 4; ++mt)
      afc[mt] = *(const bf16x8*)(ai + mt * 1024);
    #pragma unroll
    for (int d = 0; d < 8; ++d) {
      bf16x8 afn[4];
      if (d < 7) {
        #pragma unroll
        for (int mt = 0; mt < 4; ++mt)
          afn[mt] = *(const bf16x8*)(ai + (d + 1) * 4096 + mt * 1024);
      }
      __builtin_amdgcn_s_setprio(1);
      #pragma unroll
      for (int mt = 0; mt < 4; ++mt)
        #pragma unroll
        for (int nt = 0; nt < 4; ++nt)
          acc[mt][nt] = __builtin_amdgcn_mfma_f32_16x16x32_bf16(
              afc[mt], bfr[d][nt], acc[mt][nt], 0, 0, 0);
      __builtin_amdgcn_s_setprio(0);
      if (d < 7) {
        #pragma unroll
        for (int mt = 0; mt < 4; ++mt) afc[mt] = afn[mt];
      }
    }
  }

  // epilogue: C/D layout col = lane&15, row = (lane>>4)*4 + q  (m89/m91)
  #pragma unroll
  for (int nt = 0; nt < 4; ++nt) {
    int c = (tile0 + nt) * 16 + row16;
    float bv = bias[c];
    #pragma unroll
    for (int mt = 0; mt < 4; ++mt) {
      int r0 = base_row + mt * 16 + kg * 4;
      #pragma unroll
      for (int q = 0; q < 4; ++q)
        out[(size_t)(r0 + q) * NOUT + c] = acc[mt][nt][q] + bv;
    }
  }
}

extern "C" void kernel_launch(void* const* d_in, const int* in_sizes, int n_in,
                              void* d_out, int out_size, void* d_ws, size_t ws_size,
                              hipStream_t stream) {
  const float* x  = (const float*)d_in[0];
  const float* cb = (const float*)d_in[1];   // c_basis (256,256,9)
  const float* ca = (const float*)d_in[2];   // c_act   (256,256)
  float* out = (float*)d_out;

  unsigned short* Bp = (unsigned short*)d_ws;                    // 1 MB
  float* bias = (float*)((char*)d_ws + 8 * NIN * NOUT * 2);      // 1 KB

  cheby_prepack<<<(8 * NIN * NOUT) / 256, 256, 0, stream>>>(cb, ca, Bp);
  cheby_bias<<<NOUT, 64, 0, stream>>>(cb, ca, bias);
  cheby_mfma<<<512, 256, 0, stream>>>(x, Bp, bias, out);
}

// Round 9
// 47.762 us; speedup vs baseline: 1.0861x; 1.0861x over previous
//
#include <hip/hip_runtime.h>
#include <hip/hip_bf16.h>

// Problem constants
#define BATCH 32768
#define NIN   256
#define NOUT  256
// degrees 1..8 via MFMA; degree 0 (T_0 = 1) folded into per-column bias

typedef __attribute__((ext_vector_type(8))) short bf16x8;
typedef __attribute__((ext_vector_type(4))) float f32x4;
typedef __attribute__((ext_vector_type(2))) float f32x2;
typedef __attribute__((ext_vector_type(4))) unsigned int u32x4;

static __device__ __forceinline__ unsigned short bf16_rne(float f) {
  unsigned u = __float_as_uint(f);
  u += 0x7fffu + ((u >> 16) & 1u);
  return (unsigned short)(u >> 16);
}

// fast tanh: t = sign(v) * (1 - z) / (1 + z), z = exp(-2|v|)
static __device__ __forceinline__ float fast_tanh(float v) {
  float a = fabsf(v);
  float z = __expf(-2.0f * a);
  float r = (1.0f - z) * __builtin_amdgcn_rcpf(1.0f + z);
  return copysignf(r, v);
}

static __device__ __forceinline__ unsigned pack_pair(f32x2 v) {
  __hip_bfloat162 h2 = __float22bfloat162_rn(make_float2(v[0], v[1]));
  union { __hip_bfloat162 h; unsigned u; } cv;
  cv.h = h2;
  return cv.u;
}

static __device__ __forceinline__ void init_state(const f32x4 x0, const f32x4 x1,
                                                  f32x2* cur, f32x2* prev,
                                                  f32x2* t2) {
  #pragma unroll
  for (int p = 0; p < 4; ++p) {
    float va = (p < 2) ? x0[2 * p]     : x1[2 * p - 4];
    float vb = (p < 2) ? x0[2 * p + 1] : x1[2 * p - 3];
    float ta = fast_tanh(va);
    float tb = fast_tanh(vb);
    cur[p]  = (f32x2){ta, tb};        // T_1
    t2[p]   = cur[p] + cur[p];
    prev[p] = (f32x2){1.0f, 1.0f};    // T_0
  }
}

// raw barrier (no vmcnt drain) with scheduler fences
static __device__ __forceinline__ void phase_barrier() {
  __builtin_amdgcn_sched_barrier(0);
  __builtin_amdgcn_s_barrier();
  __builtin_amdgcn_sched_barrier(0);
}

// ---------------------------------------------------------------------------
// Prepack: Bp[((dm*8+ic)*16+tile)*512 + kg*128 + col*8 + j] =
//          bf16( c_basis[n][i][dm+1] * c_act[n][i] )
//   with i = ic*32 + kg*8 + j,  n = tile*16 + col.
// ---------------------------------------------------------------------------
__global__ void cheby_prepack(const float* __restrict__ cb,
                              const float* __restrict__ ca,
                              unsigned short* __restrict__ Bp) {
  int tid = blockIdx.x * 256 + threadIdx.x;
  int j    = tid & 7;
  int col  = (tid >> 3) & 15;
  int kg   = (tid >> 7) & 3;
  int tile = (tid >> 9) & 15;
  int ic   = (tid >> 13) & 7;
  int dm   = tid >> 16;           // d-1, 0..7
  int i = ic * 32 + kg * 8 + j;
  int n = tile * 16 + col;
  float w = cb[n * (NIN * 9) + i * 9 + (dm + 1)] * ca[n * NIN + i];
  Bp[tid] = bf16_rne(w);
}

// bias[n] = sum_i c_basis[n][i][0] * c_act[n][i]   (T_0 == 1 term)
__global__ void cheby_bias(const float* __restrict__ cb,
                           const float* __restrict__ ca,
                           float* __restrict__ bias) {
  int n = blockIdx.x;
  int l = threadIdx.x;            // 64 threads = one wave
  float s = 0.0f;
  #pragma unroll
  for (int k = 0; k < 4; ++k) {
    int i = l + k * 64;
    s += cb[n * (NIN * 9) + i * 9] * ca[n * NIN + i];
  }
  #pragma unroll
  for (int off = 32; off; off >>= 1) s += __shfl_down(s, off);
  if (l == 0) bias[n] = s;
}

// ---------------------------------------------------------------------------
// Fused cheby + GEMM, 8-phase pipelined (T3+T4).
// Grid: 512 blocks x 256 threads (4 waves). Block tile: 64 rows x 256 cols
// (block spans ALL cols -> basis computed once per x element globally).
// Flat pipeline over 64 steps (ic 0..7 x degree-phase p 0..7). Per phase:
//   { ds_read A-frags(step+1)  ||  issue 4 B-loads(step+1)  ||
//     one basis degree-slice of ic+1 -> ds_write buf^1 }  ->  s_barrier ->
//   16 MFMA on (af[p&1], bfr[p&1]).
// B loads always 1 phase deep -> compiler emits counted vmcnt (never 0).
// Writes go to buf^1 / the d-plane disjointness at the ic boundary makes
// one barrier per phase race-free. Last ic runs barrier-free.
// ---------------------------------------------------------------------------
__global__ __launch_bounds__(256, 2)
void cheby_mfma(const float* __restrict__ x,
                const unsigned short* __restrict__ Bp,
                const float* __restrict__ bias,
                float* __restrict__ out) {
  // [buf][d-1][mt][frag: kg*256B + row16*16B]  -- 1KB fragments, 64KB total
  __shared__ unsigned short Asm[2][8][4][512];

  int tid  = threadIdx.x;
  int w    = tid >> 6;
  int lane = tid & 63;
  int row16 = lane & 15;          // A row / B col / C-D col
  int kg    = lane >> 4;          // k-group 0..3

  int base_row = blockIdx.x * 64;
  int tile0    = w * 4;           // wave's 4 column tiles (64 cols)

  // writer role: wave w covers rows w*16..w*16+15 (plane mt=w)
  const float* xw = x + (size_t)(base_row + w * 16 + row16) * NIN + kg * 8;
  char* wbase = (char*)Asm + (w * 1024 + lane * 16);
  // reader
  const char* abase   = (const char*)Asm + lane * 16;
  const char* bp_lane = (const char*)Bp + kg * 256 + row16 * 16;

  f32x4 acc[4][4];
  #pragma unroll
  for (int a = 0; a < 4; ++a)
    #pragma unroll
    for (int b = 0; b < 4; ++b) acc[a][b] = (f32x4)0.0f;

  // ---- prologue: full basis(0) -> buf0 ----
  f32x4 xa = *(const f32x4*)xw;
  f32x4 xb = *(const f32x4*)(xw + 4);
  {
    f32x2 c0[4], p0[4], t0[4];
    init_state(xa, xb, c0, p0, t0);
    #pragma unroll
    for (int d = 1; d <= 8; ++d) {
      u32x4 pk;
      #pragma unroll
      for (int q = 0; q < 4; ++q) pk[q] = pack_pair(c0[q]);
      *(u32x4*)(wbase + (d - 1) * 4096) = pk;
      if (d < 8) {
        #pragma unroll
        for (int q = 0; q < 4; ++q) {
          f32x2 nx = __builtin_elementwise_fma(t0[q], c0[q], -p0[q]);
          p0[q] = c0[q];
          c0[q] = nx;
        }
      }
    }
  }
  // x(1) + recurrence state for basis(1)
  xa = *(const f32x4*)(xw + 32);
  xb = *(const f32x4*)(xw + 36);
  f32x2 cur[4], prev[4], t2[4];
  init_state(xa, xb, cur, prev, t2);

  bf16x8 af[2][4], bfr[2][4];
  // B for step (0,0)
  {
    const char* bp0 = bp_lane + (size_t)tile0 * 1024;
    #pragma unroll
    for (int nt = 0; nt < 4; ++nt)
      bfr[0][nt] = *(const bf16x8*)(bp0 + nt * 1024);
  }
  // make basis(0) visible, then read A(0,0)
  __builtin_amdgcn_sched_barrier(0);
  asm volatile("s_waitcnt lgkmcnt(0)" ::: "memory");
  __builtin_amdgcn_s_barrier();
  __builtin_amdgcn_sched_barrier(0);
  #pragma unroll
  for (int mt = 0; mt < 4; ++mt)
    af[0][mt] = *(const bf16x8*)(abase + mt * 1024);

  // ---- main loop: ic = 0..6 (basis for ic+1 distributed over 8 phases) ----
  for (int ic = 0; ic < 7; ++ic) {
    const char* ai   = abase + (ic & 1) * 32768;
    const char* ain  = abase + ((ic + 1) & 1) * 32768;
    char*       wp   = wbase + ((ic + 1) & 1) * 32768;
    const char* bpi  = bp_lane + (size_t)(ic * 16 + tile0) * 1024;
    const char* bpin = bp_lane + (size_t)((ic + 1) * 16 + tile0) * 1024;

    #pragma unroll
    for (int p = 0; p < 8; ++p) {
      // A-frags for next step
      if (p < 7) {
        #pragma unroll
        for (int mt = 0; mt < 4; ++mt)
          af[(p + 1) & 1][mt] =
              *(const bf16x8*)(ai + (p + 1) * 4096 + mt * 1024);
      } else {
        #pragma unroll
        for (int mt = 0; mt < 4; ++mt)
          af[0][mt] = *(const bf16x8*)(ain + mt * 1024);
      }
      // B-frags for next step (1-deep prefetch, counted vmcnt at use)
      if (p < 7) {
        #pragma unroll
        for (int nt = 0; nt < 4; ++nt)
          bfr[(p + 1) & 1][nt] =
              *(const bf16x8*)(bpi + (size_t)(p + 1) * 131072 + nt * 1024);
      } else {
        #pragma unroll
        for (int nt = 0; nt < 4; ++nt)
          bfr[0][nt] = *(const bf16x8*)(bpin + nt * 1024);
      }
      // basis degree-slice: write T_{p+1}(ic+1), advance recurrence
      {
        u32x4 pk;
        #pragma unroll
        for (int q = 0; q < 4; ++q) pk[q] = pack_pair(cur[q]);
        *(u32x4*)(wp + p * 4096) = pk;
        if (p < 7) {
          #pragma unroll
          for (int q = 0; q < 4; ++q) {
            f32x2 nx = __builtin_elementwise_fma(t2[q], cur[q], -prev[q]);
            prev[q] = cur[q];
            cur[q]  = nx;
          }
        }
      }
      if (p == 3 && ic <= 5) {     // x for ic+2 (used at p==7)
        xa = *(const f32x4*)(xw + (ic + 2) * 32);
        xb = *(const f32x4*)(xw + (ic + 2) * 32 + 4);
      }
      if (p == 7 && ic <= 5)       // state for basis(ic+2)
        init_state(xa, xb, cur, prev, t2);

      phase_barrier();

      __builtin_amdgcn_s_setprio(1);
      #pragma unroll
      for (int mt = 0; mt < 4; ++mt)
        #pragma unroll
        for (int nt = 0; nt < 4; ++nt)
          acc[mt][nt] = __builtin_amdgcn_mfma_f32_16x16x32_bf16(
              af[p & 1][mt], bfr[p & 1][nt], acc[mt][nt], 0, 0, 0);
      __builtin_amdgcn_s_setprio(0);
    }
  }

  // ---- final ic = 7: no basis work, barrier-free ----
  {
    const char* ai  = abase + 32768;                       // buf1
    const char* bpi = bp_lane + (size_t)(7 * 16 + tile0) * 1024;
    #pragma unroll
    for (int p = 0; p < 8; ++p) {
      if (p < 7) {
        #pragma unroll
        for (int mt = 0; mt < 4; ++mt)
          af[(p + 1) & 1][mt] =
              *(const bf16x8*)(ai + (p + 1) * 4096 + mt * 1024);
        #pragma unroll
        for (int nt = 0; nt < 4; ++nt)
          bfr[(p + 1) & 1][nt] =
              *(const bf16x8*)(bpi + (size_t)(p + 1) * 131072 + nt * 1024);
      }
      __builtin_amdgcn_s_setprio(1);
      #pragma unroll
      for (int mt = 0; mt < 4; ++mt)
        #pragma unroll
        for (int nt = 0; nt < 4; ++nt)
          acc[mt][nt] = __builtin_amdgcn_mfma_f32_16x16x32_bf16(
              af[p & 1][mt], bfr[p & 1][nt], acc[mt][nt], 0, 0, 0);
      __builtin_amdgcn_s_setprio(0);
    }
  }

  // epilogue: C/D layout col = lane&15, row = (lane>>4)*4 + q  (m89/m91)
  #pragma unroll
  for (int nt = 0; nt < 4; ++nt) {
    int c = (tile0 + nt) * 16 + row16;
    float bv = bias[c];
    #pragma unroll
    for (int mt = 0; mt < 4; ++mt) {
      int r0 = base_row + mt * 16 + kg * 4;
      #pragma unroll
      for (int q = 0; q < 4; ++q)
        out[(size_t)(r0 + q) * NOUT + c] = acc[mt][nt][q] + bv;
    }
  }
}

extern "C" void kernel_launch(void* const* d_in, const int* in_sizes, int n_in,
                              void* d_out, int out_size, void* d_ws, size_t ws_size,
                              hipStream_t stream) {
  const float* x  = (const float*)d_in[0];
  const float* cb = (const float*)d_in[1];   // c_basis (256,256,9)
  const float* ca = (const float*)d_in[2];   // c_act   (256,256)
  float* out = (float*)d_out;

  unsigned short* Bp = (unsigned short*)d_ws;                    // 1 MB
  float* bias = (float*)((char*)d_ws + 8 * NIN * NOUT * 2);      // 1 KB

  cheby_prepack<<<(8 * NIN * NOUT) / 256, 256, 0, stream>>>(cb, ca, Bp);
  cheby_bias<<<NOUT, 64, 0, stream>>>(cb, ca, bias);
  cheby_mfma<<<512, 256, 0, stream>>>(x, Bp, bias, out);
}

// Round 10
// 47.753 us; speedup vs baseline: 1.0863x; 1.0002x over previous
//
#include <hip/hip_runtime.h>
#include <hip/hip_bf16.h>

// Problem constants
#define BATCH 32768
#define NIN   256
#define NOUT  256
// degrees 1..8 via MFMA; degree 0 (T_0 = 1) folded into per-column bias

typedef __attribute__((ext_vector_type(8))) short bf16x8;
typedef __attribute__((ext_vector_type(4))) float f32x4;
typedef __attribute__((ext_vector_type(2))) float f32x2;
typedef __attribute__((ext_vector_type(4))) unsigned int u32x4;

static __device__ __forceinline__ unsigned short bf16_rne(float f) {
  unsigned u = __float_as_uint(f);
  u += 0x7fffu + ((u >> 16) & 1u);
  return (unsigned short)(u >> 16);
}

// fast tanh: t = sign(v) * (1 - z) / (1 + z), z = exp(-2|v|)
static __device__ __forceinline__ float fast_tanh(float v) {
  float a = fabsf(v);
  float z = __expf(-2.0f * a);
  float r = (1.0f - z) * __builtin_amdgcn_rcpf(1.0f + z);
  return copysignf(r, v);
}

static __device__ __forceinline__ unsigned pack_pair(f32x2 v) {
  __hip_bfloat162 h2 = __float22bfloat162_rn(make_float2(v[0], v[1]));
  union { __hip_bfloat162 h; unsigned u; } cv;
  cv.h = h2;
  return cv.u;
}

static __device__ __forceinline__ void init_state(const f32x4 x0, const f32x4 x1,
                                                  f32x2* cur, f32x2* prev,
                                                  f32x2* t2) {
  #pragma unroll
  for (int p = 0; p < 4; ++p) {
    float va = (p < 2) ? x0[2 * p]     : x1[2 * p - 4];
    float vb = (p < 2) ? x0[2 * p + 1] : x1[2 * p - 3];
    float ta = fast_tanh(va);
    float tb = fast_tanh(vb);
    cur[p]  = (f32x2){ta, tb};        // T_1
    t2[p]   = cur[p] + cur[p];
    prev[p] = (f32x2){1.0f, 1.0f};    // T_0
  }
}

// raw barrier (no vmcnt drain) with scheduler fences
static __device__ __forceinline__ void phase_barrier() {
  __builtin_amdgcn_sched_barrier(0);
  __builtin_amdgcn_s_barrier();
  __builtin_amdgcn_sched_barrier(0);
}

// ---------------------------------------------------------------------------
// Prepack: Bp[((dm*8+ic)*16+tile)*512 + kg*128 + col*8 + j] =
//          bf16( c_basis[n][i][dm+1] * c_act[n][i] )
//   with i = ic*32 + kg*8 + j,  n = tile*16 + col.
// ---------------------------------------------------------------------------
__global__ void cheby_prepack(const float* __restrict__ cb,
                              const float* __restrict__ ca,
                              unsigned short* __restrict__ Bp) {
  int tid = blockIdx.x * 256 + threadIdx.x;
  int j    = tid & 7;
  int col  = (tid >> 3) & 15;
  int kg   = (tid >> 7) & 3;
  int tile = (tid >> 9) & 15;
  int ic   = (tid >> 13) & 7;
  int dm   = tid >> 16;           // d-1, 0..7
  int i = ic * 32 + kg * 8 + j;
  int n = tile * 16 + col;
  float w = cb[n * (NIN * 9) + i * 9 + (dm + 1)] * ca[n * NIN + i];
  Bp[tid] = bf16_rne(w);
}

// bias[n] = sum_i c_basis[n][i][0] * c_act[n][i]   (T_0 == 1 term)
__global__ void cheby_bias(const float* __restrict__ cb,
                           const float* __restrict__ ca,
                           float* __restrict__ bias) {
  int n = blockIdx.x;
  int l = threadIdx.x;            // 64 threads = one wave
  float s = 0.0f;
  #pragma unroll
  for (int k = 0; k < 4; ++k) {
    int i = l + k * 64;
    s += cb[n * (NIN * 9) + i * 9] * ca[n * NIN + i];
  }
  #pragma unroll
  for (int off = 32; off; off >>= 1) s += __shfl_down(s, off);
  if (l == 0) bias[n] = s;
}

// ---------------------------------------------------------------------------
// Fused cheby + GEMM, 8-phase pipelined, 128-row blocks (halved B/L2 traffic).
// Grid: 256 blocks x 512 threads (8 waves) -> 1 block/CU, LDS 128KB.
// Block tile: 128 rows x 256 cols. Wave tile: 64x64 (wr=w>>2 row half,
// wc=w&3 col strip). Each block reads Bp (1MB) ONCE per K-pass ->
// per-CU L2 demand ~26 B/cy (46% of ceiling) vs 52 B/cy before (93%).
// Basis computed exactly once per x element (wave w writes plane w).
// Per phase: { ds_read A(next) || 4 B-loads(next) || basis slice(ic+1) }
// -> s_barrier -> 16 MFMA.
// ---------------------------------------------------------------------------
__global__ __launch_bounds__(512, 2)
void cheby_mfma(const float* __restrict__ x,
                const unsigned short* __restrict__ Bp,
                const float* __restrict__ bias,
                float* __restrict__ out) {
  // [buf][d-1][mt 0..7][frag: kg*256B + row16*16B] -- 1KB planes, 128KB total
  __shared__ unsigned short Asm[2][8][8][512];

  int tid  = threadIdx.x;
  int w    = tid >> 6;            // 0..7
  int lane = tid & 63;
  int row16 = lane & 15;          // A row / B col / C-D col
  int kg    = lane >> 4;          // k-group 0..3

  int wr = w >> 2;                // row half (0..1)
  int wc = w & 3;                 // col strip (0..3)
  int base_row = blockIdx.x * 128;
  int tile0    = wc * 4;          // wave's 4 column tiles (64 cols)

  // writer role: wave w covers rows w*16..w*16+15 (plane mt=w)
  const float* xw = x + (size_t)(base_row + w * 16 + row16) * NIN + kg * 8;
  char* wbase = (char*)Asm + (w * 1024 + lane * 16);   // + d*8192 + buf*65536
  // reader
  const char* abase   = (const char*)Asm + lane * 16;  // + plane*1024 ...
  const char* bp_lane = (const char*)Bp + kg * 256 + row16 * 16;

  f32x4 acc[4][4];
  #pragma unroll
  for (int a = 0; a < 4; ++a)
    #pragma unroll
    for (int b = 0; b < 4; ++b) acc[a][b] = (f32x4)0.0f;

  // ---- prologue: full basis(0) -> buf0 ----
  f32x4 xa = *(const f32x4*)xw;
  f32x4 xb = *(const f32x4*)(xw + 4);
  {
    f32x2 c0[4], p0[4], t0[4];
    init_state(xa, xb, c0, p0, t0);
    #pragma unroll
    for (int d = 1; d <= 8; ++d) {
      u32x4 pk;
      #pragma unroll
      for (int q = 0; q < 4; ++q) pk[q] = pack_pair(c0[q]);
      *(u32x4*)(wbase + (d - 1) * 8192) = pk;
      if (d < 8) {
        #pragma unroll
        for (int q = 0; q < 4; ++q) {
          f32x2 nx = __builtin_elementwise_fma(t0[q], c0[q], -p0[q]);
          p0[q] = c0[q];
          c0[q] = nx;
        }
      }
    }
  }
  // x(1) + recurrence state for basis(1)
  xa = *(const f32x4*)(xw + 32);
  xb = *(const f32x4*)(xw + 36);
  f32x2 cur[4], prev[4], t2[4];
  init_state(xa, xb, cur, prev, t2);

  bf16x8 af[2][4], bfr[2][4];
  // B for step (0,0)
  {
    const char* bp0 = bp_lane + (size_t)tile0 * 1024;
    #pragma unroll
    for (int nt = 0; nt < 4; ++nt)
      bfr[0][nt] = *(const bf16x8*)(bp0 + nt * 1024);
  }
  // make basis(0) visible, then read A(0,0)
  __builtin_amdgcn_sched_barrier(0);
  asm volatile("s_waitcnt lgkmcnt(0)" ::: "memory");
  __builtin_amdgcn_s_barrier();
  __builtin_amdgcn_sched_barrier(0);
  #pragma unroll
  for (int mt = 0; mt < 4; ++mt)
    af[0][mt] = *(const bf16x8*)(abase + (wr * 4 + mt) * 1024);

  // ---- main loop: ic = 0..6 (basis for ic+1 distributed over 8 phases) ----
  for (int ic = 0; ic < 7; ++ic) {
    const char* ai   = abase + (ic & 1) * 65536 + (wr * 4) * 1024;
    const char* ain  = abase + ((ic + 1) & 1) * 65536 + (wr * 4) * 1024;
    char*       wp   = wbase + ((ic + 1) & 1) * 65536;
    const char* bpi  = bp_lane + (size_t)(ic * 16 + tile0) * 1024;
    const char* bpin = bp_lane + (size_t)((ic + 1) * 16 + tile0) * 1024;

    #pragma unroll
    for (int p = 0; p < 8; ++p) {
      // A-frags for next step
      if (p < 7) {
        #pragma unroll
        for (int mt = 0; mt < 4; ++mt)
          af[(p + 1) & 1][mt] =
              *(const bf16x8*)(ai + (p + 1) * 8192 + mt * 1024);
      } else {
        #pragma unroll
        for (int mt = 0; mt < 4; ++mt)
          af[0][mt] = *(const bf16x8*)(ain + mt * 1024);
      }
      // B-frags for next step (1-deep prefetch, counted vmcnt at use)
      if (p < 7) {
        #pragma unroll
        for (int nt = 0; nt < 4; ++nt)
          bfr[(p + 1) & 1][nt] =
              *(const bf16x8*)(bpi + (size_t)(p + 1) * 131072 + nt * 1024);
      } else {
        #pragma unroll
        for (int nt = 0; nt < 4; ++nt)
          bfr[0][nt] = *(const bf16x8*)(bpin + nt * 1024);
      }
      // basis degree-slice: write T_{p+1}(ic+1), advance recurrence
      {
        u32x4 pk;
        #pragma unroll
        for (int q = 0; q < 4; ++q) pk[q] = pack_pair(cur[q]);
        *(u32x4*)(wp + p * 8192) = pk;
        if (p < 7) {
          #pragma unroll
          for (int q = 0; q < 4; ++q) {
            f32x2 nx = __builtin_elementwise_fma(t2[q], cur[q], -prev[q]);
            prev[q] = cur[q];
            cur[q]  = nx;
          }
        }
      }
      if (p == 3 && ic <= 5) {     // x for ic+2 (used at p==7)
        xa = *(const f32x4*)(xw + (ic + 2) * 32);
        xb = *(const f32x4*)(xw + (ic + 2) * 32 + 4);
      }
      if (p == 7 && ic <= 5)       // state for basis(ic+2)
        init_state(xa, xb, cur, prev, t2);

      phase_barrier();

      __builtin_amdgcn_s_setprio(1);
      #pragma unroll
      for (int mt = 0; mt < 4; ++mt)
        #pragma unroll
        for (int nt = 0; nt < 4; ++nt)
          acc[mt][nt] = __builtin_amdgcn_mfma_f32_16x16x32_bf16(
              af[p & 1][mt], bfr[p & 1][nt], acc[mt][nt], 0, 0, 0);
      __builtin_amdgcn_s_setprio(0);
    }
  }

  // ---- final ic = 7: no basis work, barrier-free ----
  {
    const char* ai  = abase + 65536 + (wr * 4) * 1024;     // buf1
    const char* bpi = bp_lane + (size_t)(7 * 16 + tile0) * 1024;
    #pragma unroll
    for (int p = 0; p < 8; ++p) {
      if (p < 7) {
        #pragma unroll
        for (int mt = 0; mt < 4; ++mt)
          af[(p + 1) & 1][mt] =
              *(const bf16x8*)(ai + (p + 1) * 8192 + mt * 1024);
        #pragma unroll
        for (int nt = 0; nt < 4; ++nt)
          bfr[(p + 1) & 1][nt] =
              *(const bf16x8*)(bpi + (size_t)(p + 1) * 131072 + nt * 1024);
      }
      __builtin_amdgcn_s_setprio(1);
      #pragma unroll
      for (int mt = 0; mt < 4; ++mt)
        #pragma unroll
        for (int nt = 0; nt < 4; ++nt)
          acc[mt][nt] = __builtin_amdgcn_mfma_f32_16x16x32_bf16(
              af[p & 1][mt], bfr[p & 1][nt], acc[mt][nt], 0, 0, 0);
      __builtin_amdgcn_s_setprio(0);
    }
  }

  // epilogue: C/D layout col = lane&15, row = (lane>>4)*4 + q  (m89/m91)
  #pragma unroll
  for (int nt = 0; nt < 4; ++nt) {
    int c = (tile0 + nt) * 16 + row16;
    float bv = bias[c];
    #pragma unroll
    for (int mt = 0; mt < 4; ++mt) {
      int r0 = base_row + wr * 64 + mt * 16 + kg * 4;
      #pragma unroll
      for (int q = 0; q < 4; ++q)
        out[(size_t)(r0 + q) * NOUT + c] = acc[mt][nt][q] + bv;
    }
  }
}

extern "C" void kernel_launch(void* const* d_in, const int* in_sizes, int n_in,
                              void* d_out, int out_size, void* d_ws, size_t ws_size,
                              hipStream_t stream) {
  const float* x  = (const float*)d_in[0];
  const float* cb = (const float*)d_in[1];   // c_basis (256,256,9)
  const float* ca = (const float*)d_in[2];   // c_act   (256,256)
  float* out = (float*)d_out;

  unsigned short* Bp = (unsigned short*)d_ws;                    // 1 MB
  float* bias = (float*)((char*)d_ws + 8 * NIN * NOUT * 2);      // 1 KB

  cheby_prepack<<<(8 * NIN * NOUT) / 256, 256, 0, stream>>>(cb, ca, Bp);
  cheby_bias<<<NOUT, 64, 0, stream>>>(cb, ca, bias);
  cheby_mfma<<<256, 512, 0, stream>>>(x, Bp, bias, out);
}